// Round 8
// baseline (417.616 us; speedup 1.0000x reference)
//
#include <hip/hip_runtime.h>

#define NN 10000
#define EE 100000
#define CC 32
#define GG 64
#define EPSV 1e-5f
#define NB 4               // src nodes per fused block (R8: 8->4 for occupancy)
#define SLOTS 1056         // 32*32 P-slots + 32 bias slots (w2r layout [i][slot])
#define HST 36             // h row stride (32 h + 1 one + 3 zero), 144B = 16B-aligned
#define PST 36             // P2 c-stride per o-row (c=0..31 data, 32 bias, 33..35 pad)
#define PNODE (32*PST)     // 1152 floats per node in LDS
#define EBLK (EE/8)        // 12500 edge blocks in k_init
#define WBLK 160           // w2t blocks in k_init: 5 per i, i=0..31

// ---------------- k_init: per-edge h (both layers) + degree hists + weight transpose ----
__global__ __launch_bounds__(256) void k_init(const float* __restrict__ edge_attr,
        const float* __restrict__ w1a, const float* __restrict__ b1a,
        const float* __restrict__ w1b, const float* __restrict__ b1b,
        const int* __restrict__ ei,
        float* __restrict__ hbuf1, float* __restrict__ hbuf2,
        int* __restrict__ cnt, int* __restrict__ deg,
        const float* __restrict__ w2a, const float* __restrict__ b2a,
        const float* __restrict__ w2b, const float* __restrict__ b2b,
        float* __restrict__ w2r1, float* __restrict__ w2r2) {
    int blk = blockIdx.x;
    int t = threadIdx.x;
    if (blk < EBLK) {
        int e = blk * 8 + (t >> 5);
        int o = t & 31;
        float4 a = *(const float4*)&edge_attr[(size_t)e * 4];
        float ha = fmaxf(a.x * w1a[o] + a.y * w1a[32 + o] + a.z * w1a[64 + o] + a.w * w1a[96 + o] + b1a[o], 0.f);
        float hb = fmaxf(a.x * w1b[o] + a.y * w1b[32 + o] + a.z * w1b[64 + o] + a.w * w1b[96 + o] + b1b[o], 0.f);
        hbuf1[(size_t)e * HST + o] = ha;
        hbuf2[(size_t)e * HST + o] = hb;
        if (o < 4) {
            float pad = (o == 0) ? 1.f : 0.f;
            hbuf1[(size_t)e * HST + 32 + o] = pad;
            hbuf2[(size_t)e * HST + 32 + o] = pad;
        }
        if (o == 0) {
            atomicAdd(&cnt[ei[EE + e]], 1);   // dst in-degree
            atomicAdd(&deg[ei[e]], 1);        // src out-degree
        }
    } else {
        int b2i = blk - EBLK;                 // 0..159
        int s = (b2i % 5) * 256 + t;
        int i = b2i / 5;
        if (s < SLOTS) {
            float va = (s < 1024) ? w2a[(s >> 5) * 1024 + i * 32 + (s & 31)]
                                  : b2a[i * 32 + (s - 1024)];
            float vb = (s < 1024) ? w2b[(s >> 5) * 1024 + i * 32 + (s & 31)]
                                  : b2b[i * 32 + (s - 1024)];
            w2r1[i * SLOTS + s] = va;
            w2r2[i * SLOTS + s] = vb;
        }
    }
}

// ---------------- exclusive scan of deg[NN] -> rowptr[NN+1] AND cursor copy ----------------
__global__ __launch_bounds__(1024) void k_scan(const int* __restrict__ deg,
                                               int* __restrict__ rowptr,
                                               int* __restrict__ cursor) {
    __shared__ int buf[1024];
    int t = threadIdx.x;
    int v[10]; int s = 0;
    int base = t * 10;
    #pragma unroll
    for (int k = 0; k < 10; k++) {
        int idx = base + k;
        v[k] = (idx < NN) ? deg[idx] : 0;
        s += v[k];
    }
    buf[t] = s;
    for (int off = 1; off < 1024; off <<= 1) {
        __syncthreads();
        int val = buf[t] + ((t >= off) ? buf[t - off] : 0);
        __syncthreads();
        buf[t] = val;
    }
    __syncthreads();
    int carry = (t > 0) ? buf[t - 1] : 0;
    #pragma unroll
    for (int k = 0; k < 10; k++) {
        int idx = base + k;
        if (idx < NN) { rowptr[idx] = carry; cursor[idx] = carry; }
        carry += v[k];
    }
    if (t == 1023) rowptr[NN] = buf[1023];
}

// ---------------- scatter edge ids into CSR (cursor holds absolute positions) ----------------
__global__ void k_scatter(const int* __restrict__ ei,
                          int* __restrict__ cursor, int* __restrict__ csr_eid) {
    int e = blockIdx.x * blockDim.x + threadIdx.x;
    if (e >= EE) return;
    int pos = atomicAdd(&cursor[ei[e]], 1);
    csr_eid[pos] = e;
}

// ---------------- fused NNConv: P in LDS + edge pass ----------------
// R8: NB=4 -> LDS 18,944 B/block -> ~8 blocks/CU residency (was 2-3 at 37.9 KB).
__global__ __launch_bounds__(256, 4) void k_fused3(const float* __restrict__ x,
        const float* __restrict__ hbuf,
        const float* __restrict__ w2r,
        const int* __restrict__ ei, const int* __restrict__ rowptr,
        const int* __restrict__ csr_eid, float* __restrict__ agg) {
    __shared__ float xs[NB][32];
    __shared__ float P2[NB * PNODE];     // 4*1152*4 = 18,432 B
    int t = threadIdx.x;
    int o = t & 31;
    int cb = 4 * (t >> 5);               // base c (0,4,...,28)
    int n0 = blockIdx.x * NB;

    if (t < NB * 32) xs[t >> 5][t & 31] = x[n0 * 32 + t];
    __syncthreads();

    // ---- Phase A: P2[n][o][c] = sum_i x[n,i] * w2r[i][c*32+o] ----
    {
        float acc[4][NB];
        #pragma unroll
        for (int k = 0; k < 4; k++)
            #pragma unroll
            for (int n = 0; n < NB; n++) acc[k][n] = 0.f;
        #pragma unroll
        for (int j = 0; j < 8; j++) {
            float wk[4][4];
            #pragma unroll
            for (int r = 0; r < 4; r++)
                #pragma unroll
                for (int k = 0; k < 4; k++)
                    wk[r][k] = w2r[(4 * j + r) * SLOTS + (cb + k) * 32 + o];
            #pragma unroll
            for (int n = 0; n < NB; n++) {
                float4 xq = *(const float4*)&xs[n][4 * j];
                #pragma unroll
                for (int k = 0; k < 4; k++)
                    acc[k][n] += xq.x * wk[0][k] + xq.y * wk[1][k]
                               + xq.z * wk[2][k] + xq.w * wk[3][k];
            }
        }
        #pragma unroll
        for (int n = 0; n < NB; n++) {
            float4 st = make_float4(acc[0][n], acc[1][n], acc[2][n], acc[3][n]);
            *(float4*)&P2[n * PNODE + o * PST + cb] = st;
        }
    }
    if (t < 32) {
        float wb[32];
        #pragma unroll
        for (int i = 0; i < 32; i++) wb[i] = w2r[i * SLOTS + 1024 + t];
        #pragma unroll
        for (int n = 0; n < NB; n++) {
            float b = 0.f;
            #pragma unroll
            for (int j = 0; j < 8; j++) {
                float4 xq = *(const float4*)&xs[n][4 * j];
                b += xq.x * wb[4 * j] + xq.y * wb[4 * j + 1]
                   + xq.z * wb[4 * j + 2] + xq.w * wb[4 * j + 3];
            }
            *(float4*)&P2[n * PNODE + t * PST + 32] = make_float4(b, 0.f, 0.f, 0.f);
        }
    }
    __syncthreads();

    // ---- Phase B: 32-lane group per edge; h prefetched one edge ahead ----
    int ebase = rowptr[n0];
    int eend  = rowptr[n0 + NB];
    int grp = t >> 5;
    int pos = ebase + grp;
    int e_c = 0, src_c = 0, dst_c = 0;
    float4 hq[9];
    if (pos < eend) {
        e_c = csr_eid[pos];
        src_c = ei[e_c];
        dst_c = ei[EE + e_c];
        const float* hb = &hbuf[(size_t)e_c * HST];
        #pragma unroll
        for (int b = 0; b < 9; b++) hq[b] = *(const float4*)&hb[4 * b];
    }
    while (pos < eend) {
        int pos_n = pos + 8;
        int e_n = 0, src_n = 0, dst_n = 0;
        float4 hq_n[9];
        if (pos_n < eend) {                     // prefetch next edge: indices + h data
            e_n = csr_eid[pos_n];
            src_n = ei[e_n];
            dst_n = ei[EE + e_n];
            const float* hbn = &hbuf[(size_t)e_n * HST];
            #pragma unroll
            for (int b = 0; b < 9; b++) hq_n[b] = *(const float4*)&hbn[4 * b];
        }
        const float* Pn = &P2[(src_c - n0) * PNODE + o * PST];
        float msg = 0.f;
        #pragma unroll
        for (int b = 0; b < 9; b++) {
            float4 pq = *(const float4*)&Pn[4 * b];      // ds_read_b128
            msg += hq[b].x * pq.x + hq[b].y * pq.y
                 + hq[b].z * pq.z + hq[b].w * pq.w;
        }
        atomicAdd(&agg[(size_t)dst_c * 32 + o], msg);
        pos = pos_n; e_c = e_n; src_c = src_n; dst_c = dst_n;
        #pragma unroll
        for (int b = 0; b < 9; b++) hq[b] = hq_n[b];
    }
}

// ---------------- combine: agg/cnt + x@root + bias -> BN -> ReLU ----------------
__global__ __launch_bounds__(256) void k_combine(const float* __restrict__ x_in,
        float* __restrict__ agg, const int* __restrict__ cnt,
        const float* __restrict__ root, const float* __restrict__ bias,
        const float* __restrict__ bng, const float* __restrict__ bnb,
        const float* __restrict__ bnm, const float* __restrict__ bnv,
        float* __restrict__ x_out, float* __restrict__ psum,
        const int* __restrict__ batch) {
    __shared__ float xs[8][32];
    __shared__ float vals[8][32];
    __shared__ int gb[8];
    int t = threadIdx.x;
    int n0 = blockIdx.x * 8;
    xs[t >> 5][t & 31] = x_in[n0 * 32 + t];
    __syncthreads();
    int k = t >> 5, o = t & 31, n = n0 + k;
    float r = bias[o];
    #pragma unroll
    for (int i = 0; i < 32; i++) r += xs[k][i] * root[i * 32 + o];
    float a = agg[(size_t)n * 32 + o] / fmaxf((float)cnt[n], 1.f);
    float val = a + r;
    val = (val - bnm[o]) * rsqrtf(bnv[o] + EPSV) * bng[o] + bnb[o];
    val = fmaxf(val, 0.f);
    if (x_out) {
        x_out[(size_t)n * 32 + o] = val;
        agg[(size_t)n * 32 + o] = 0.f;        // re-zero for layer 2
    }
    if (psum) {
        vals[k][o] = val;
        if (o == 0) gb[k] = batch[n];
        __syncthreads();
        if (k == 0) {
            float acc = vals[0][o];
            int g = gb[0];
            #pragma unroll
            for (int k2 = 1; k2 < 8; k2++) {
                if (gb[k2] == g) acc += vals[k2][o];
                else {
                    atomicAdd(&psum[(size_t)g * 32 + o], acc);
                    g = gb[k2]; acc = vals[k2][o];
                }
            }
            atomicAdd(&psum[(size_t)g * 32 + o], acc);
        }
    }
}

// ---------------- global mean pool + readout MLP ----------------
__global__ __launch_bounds__(256) void k_readout(const float* __restrict__ psum,
        const int* __restrict__ batch,
        const float* __restrict__ r1w, const float* __restrict__ r1b,
        const float* __restrict__ r2w, const float* __restrict__ r2b,
        float* __restrict__ out) {
    __shared__ float w1s[32 * 16];
    __shared__ float b1s[16];
    __shared__ float w2s[16];
    __shared__ float ps[GG * 32];
    int t = threadIdx.x;
    int cnt_g = 0;
    if (t < GG) {
        int lo = 0, hi = NN;
        while (lo < hi) { int m = (lo + hi) >> 1; if (batch[m] < t) lo = m + 1; else hi = m; }
        int lb = lo;
        lo = 0; hi = NN;
        while (lo < hi) { int m = (lo + hi) >> 1; if (batch[m] < t + 1) lo = m + 1; else hi = m; }
        cnt_g = lo - lb;
    }
    w1s[t] = r1w[t];
    w1s[t + 256] = r1w[t + 256];
    if (t < 16) { b1s[t] = r1b[t]; w2s[t] = r2w[t]; }
    #pragma unroll
    for (int i = 0; i < GG * 32 / 256; i++) ps[t + i * 256] = psum[t + i * 256];
    __syncthreads();
    if (t < GG) {
        float inv = 1.f / fmaxf((float)cnt_g, 1.f);
        float acc = r2b[0];
        #pragma unroll
        for (int j = 0; j < 16; j++) {
            float dot = 0.f;
            #pragma unroll
            for (int c = 0; c < 32; c++) dot += ps[t * 32 + c] * w1s[c * 16 + j];
            float z = dot * inv + b1s[j];
            acc += fmaxf(z, 0.f) * w2s[j];
        }
        out[t] = acc;
    }
}

extern "C" void kernel_launch(void* const* d_in, const int* in_sizes, int n_in,
                              void* d_out, int out_size, void* d_ws, size_t ws_size,
                              hipStream_t stream) {
    const float* x       = (const float*)d_in[0];
    const float* eattr   = (const float*)d_in[1];
    const float* e1_w1   = (const float*)d_in[2];
    const float* e1_b1   = (const float*)d_in[3];
    const float* e1_w2   = (const float*)d_in[4];
    const float* e1_b2   = (const float*)d_in[5];
    const float* root1   = (const float*)d_in[6];
    const float* bias1   = (const float*)d_in[7];
    const float* e2_w1   = (const float*)d_in[8];
    const float* e2_b1   = (const float*)d_in[9];
    const float* e2_w2   = (const float*)d_in[10];
    const float* e2_b2   = (const float*)d_in[11];
    const float* root2   = (const float*)d_in[12];
    const float* bias2   = (const float*)d_in[13];
    const float* bn1_g   = (const float*)d_in[14];
    const float* bn1_b   = (const float*)d_in[15];
    const float* bn1_m   = (const float*)d_in[16];
    const float* bn1_v   = (const float*)d_in[17];
    const float* bn2_g   = (const float*)d_in[18];
    const float* bn2_b   = (const float*)d_in[19];
    const float* bn2_m   = (const float*)d_in[20];
    const float* bn2_v   = (const float*)d_in[21];
    const float* r1_w    = (const float*)d_in[22];
    const float* r1_b    = (const float*)d_in[23];
    const float* r2_w    = (const float*)d_in[24];
    const float* r2_b    = (const float*)d_in[25];
    const int*   ei      = (const int*)d_in[26];
    const int*   batch   = (const int*)d_in[27];

    // workspace layout (bytes) — zeroed buffers contiguous for a single memset
    char* ws = (char*)d_ws;
    float* hbuf1  = (float*)(ws);                   // 14,400,000
    float* hbuf2  = (float*)(ws + 14400000);        // 14,400,000
    float* w2r1   = (float*)(ws + 28800000);        // 135,168
    float* w2r2   = (float*)(ws + 28935168);        // 135,168
    // ---- zero region start (1,368,192 B) ----
    float* agg    = (float*)(ws + 29070336);        // 1,280,000
    int*   cnt    = (int*)  (ws + 30350336);        // 40,000
    int*   deg    = (int*)  (ws + 30390336);        // 40,000
    float* psum   = (float*)(ws + 30430336);        // 8,192
    // ---- zero region end ----
    float* xmid   = (float*)(ws + 30438528);        // 1,280,000
    int*   rowptr = (int*)  (ws + 31718528);        // 40,064
    int*   cursor = (int*)  (ws + 31758592);        // 40,000
    int*   csr    = (int*)  (ws + 31798592);        // 400,000
    // total ~32.2 MB

    hipMemsetAsync(ws + 29070336, 0, 1368192, stream);   // agg+cnt+deg+psum

    // h (both layers) + degree hists + weight transposes — one dispatch
    k_init<<<EBLK + WBLK, 256, 0, stream>>>(eattr, e1_w1, e1_b1, e2_w1, e2_b1, ei,
                                            hbuf1, hbuf2, cnt, deg,
                                            e1_w2, e1_b2, e2_w2, e2_b2, w2r1, w2r2);
    k_scan<<<1, 1024, 0, stream>>>(deg, rowptr, cursor);
    k_scatter<<<(EE + 255) / 256, 256, 0, stream>>>(ei, cursor, csr);

    // ---- layer 1 ----
    k_fused3<<<NN / NB, 256, 0, stream>>>(x, hbuf1, w2r1, ei, rowptr, csr, agg);
    k_combine<<<NN / 8, 256, 0, stream>>>(x, agg, cnt, root1, bias1,
                                          bn1_g, bn1_b, bn1_m, bn1_v,
                                          xmid, nullptr, batch);

    // ---- layer 2 ----
    k_fused3<<<NN / NB, 256, 0, stream>>>(xmid, hbuf2, w2r2, ei, rowptr, csr, agg);
    k_combine<<<NN / 8, 256, 0, stream>>>(xmid, agg, cnt, root2, bias2,
                                          bn2_g, bn2_b, bn2_m, bn2_v,
                                          nullptr, psum, batch);

    // ---- pool + readout ----
    k_readout<<<1, 256, 0, stream>>>(psum, batch, r1_w, r1_b, r2_w, r2_b, (float*)d_out);
}

// Round 10
// 325.368 us; speedup vs baseline: 1.2835x; 1.2835x over previous
//
#include <hip/hip_runtime.h>

#define NN 10000
#define EE 100000
#define CC 32
#define GG 64
#define EPSV 1e-5f
#define NB 4               // src nodes per fused block
#define SLOTS 1056         // 32*32 P-slots + 32 bias slots (w2r layout [i][slot])
#define PST 36             // P2 c-stride per o-row (c=0..31 data, 32 bias, 33..35 pad)
#define PNODE (32*PST)     // 1152 floats per node in LDS
#define EBLK (EE/8)        // 12500 edge blocks in k_init
#define WBLK 160           // w2t blocks in k_init: 5 per i, i=0..31

// ---------------- k_init: per-edge h (both layers, 32 f/edge) + hists + w transpose ----
__global__ __launch_bounds__(256) void k_init(const float* __restrict__ edge_attr,
        const float* __restrict__ w1a, const float* __restrict__ b1a,
        const float* __restrict__ w1b, const float* __restrict__ b1b,
        const int* __restrict__ ei,
        float* __restrict__ hbuf1, float* __restrict__ hbuf2,
        int* __restrict__ cnt, int* __restrict__ deg,
        const float* __restrict__ w2a, const float* __restrict__ b2a,
        const float* __restrict__ w2b, const float* __restrict__ b2b,
        float* __restrict__ w2r1, float* __restrict__ w2r2) {
    int blk = blockIdx.x;
    int t = threadIdx.x;
    if (blk < EBLK) {
        int e = blk * 8 + (t >> 5);
        int o = t & 31;
        float4 a = *(const float4*)&edge_attr[(size_t)e * 4];
        float ha = fmaxf(a.x * w1a[o] + a.y * w1a[32 + o] + a.z * w1a[64 + o] + a.w * w1a[96 + o] + b1a[o], 0.f);
        float hb = fmaxf(a.x * w1b[o] + a.y * w1b[32 + o] + a.z * w1b[64 + o] + a.w * w1b[96 + o] + b1b[o], 0.f);
        hbuf1[(size_t)e * 32 + o] = ha;
        hbuf2[(size_t)e * 32 + o] = hb;
        if (o == 0) {
            atomicAdd(&cnt[ei[EE + e]], 1);   // dst in-degree (int: deterministic)
            atomicAdd(&deg[ei[e]], 1);        // src out-degree
        }
    } else {
        int b2i = blk - EBLK;                 // 0..159
        int s = (b2i % 5) * 256 + t;
        int i = b2i / 5;
        if (s < SLOTS) {
            float va = (s < 1024) ? w2a[(s >> 5) * 1024 + i * 32 + (s & 31)]
                                  : b2a[i * 32 + (s - 1024)];
            float vb = (s < 1024) ? w2b[(s >> 5) * 1024 + i * 32 + (s & 31)]
                                  : b2b[i * 32 + (s - 1024)];
            w2r1[i * SLOTS + s] = va;
            w2r2[i * SLOTS + s] = vb;
        }
    }
}

// ---------------- two exclusive scans: deg->rowptr_s/cursor_s, cnt->rowptr_d/cursor_d ----
__global__ __launch_bounds__(1024) void k_scan2(const int* __restrict__ deg,
        const int* __restrict__ cnt,
        int* __restrict__ rowptr_s, int* __restrict__ cursor_s,
        int* __restrict__ rowptr_d, int* __restrict__ cursor_d) {
    __shared__ int buf[1024];
    int t = threadIdx.x;
    int base = t * 10;
    for (int pass = 0; pass < 2; pass++) {
        const int* in = (pass == 0) ? deg : cnt;
        int* rp = (pass == 0) ? rowptr_s : rowptr_d;
        int* cu = (pass == 0) ? cursor_s : cursor_d;
        int v[10]; int s = 0;
        #pragma unroll
        for (int k = 0; k < 10; k++) {
            int idx = base + k;
            v[k] = (idx < NN) ? in[idx] : 0;
            s += v[k];
        }
        __syncthreads();           // buf reuse safety (pass 1)
        buf[t] = s;
        for (int off = 1; off < 1024; off <<= 1) {
            __syncthreads();
            int val = buf[t] + ((t >= off) ? buf[t - off] : 0);
            __syncthreads();
            buf[t] = val;
        }
        __syncthreads();
        int carry = (t > 0) ? buf[t - 1] : 0;
        #pragma unroll
        for (int k = 0; k < 10; k++) {
            int idx = base + k;
            if (idx < NN) { rp[idx] = carry; cu[idx] = carry; }
            carry += v[k];
        }
        if (t == 1023) rp[NN] = buf[1023];
    }
}

// ---------------- scatter edge ids into BOTH CSRs ----------------
__global__ void k_scatter2(const int* __restrict__ ei,
                           int* __restrict__ cursor_s, int* __restrict__ csr_s,
                           int* __restrict__ cursor_d, int* __restrict__ csr_d) {
    int e = blockIdx.x * blockDim.x + threadIdx.x;
    if (e >= EE) return;
    int ps = atomicAdd(&cursor_s[ei[e]], 1);
    csr_s[ps] = e;
    int pd = atomicAdd(&cursor_d[ei[EE + e]], 1);
    csr_d[pd] = e;
}

// ---------------- sort each dst row by edge id (determinism of gather order) ----------------
__global__ void k_sortrows(const int* __restrict__ rowptr_d, int* __restrict__ csr_d) {
    int n = blockIdx.x * blockDim.x + threadIdx.x;
    if (n >= NN) return;
    int lo = rowptr_d[n], hi = rowptr_d[n + 1];
    for (int i = lo + 1; i < hi; i++) {
        int v = csr_d[i];
        int j = i - 1;
        while (j >= lo && csr_d[j] > v) { csr_d[j + 1] = csr_d[j]; j--; }
        csr_d[j + 1] = v;
    }
}

// ---------------- fused NNConv: P in LDS + per-edge message -> msgbuf (NO atomics) -------
__global__ __launch_bounds__(256, 3) void k_fused3(const float* __restrict__ x,
        const float* __restrict__ hbuf,
        const float* __restrict__ w2r,
        const int* __restrict__ ei, const int* __restrict__ rowptr_s,
        const int* __restrict__ csr_s, float* __restrict__ msgbuf) {
    __shared__ float xs[NB][32];
    __shared__ float P2[NB * PNODE];     // 4*1152*4 = 18,432 B
    int t = threadIdx.x;
    int o = t & 31;
    int cb = 4 * (t >> 5);               // base c (0,4,...,28)
    int n0 = blockIdx.x * NB;

    if (t < NB * 32) xs[t >> 5][t & 31] = x[n0 * 32 + t];
    __syncthreads();

    // ---- Phase A: P2[n][o][c] = sum_i x[n,i] * w2r[i][c*32+o]; bias at slot 32 ----
    {
        float acc[4][NB];
        #pragma unroll
        for (int k = 0; k < 4; k++)
            #pragma unroll
            for (int n = 0; n < NB; n++) acc[k][n] = 0.f;
        #pragma unroll
        for (int j = 0; j < 8; j++) {
            float wk[4][4];
            #pragma unroll
            for (int r = 0; r < 4; r++)
                #pragma unroll
                for (int k = 0; k < 4; k++)
                    wk[r][k] = w2r[(4 * j + r) * SLOTS + (cb + k) * 32 + o];
            #pragma unroll
            for (int n = 0; n < NB; n++) {
                float4 xq = *(const float4*)&xs[n][4 * j];
                #pragma unroll
                for (int k = 0; k < 4; k++)
                    acc[k][n] += xq.x * wk[0][k] + xq.y * wk[1][k]
                               + xq.z * wk[2][k] + xq.w * wk[3][k];
            }
        }
        #pragma unroll
        for (int n = 0; n < NB; n++) {
            float4 st = make_float4(acc[0][n], acc[1][n], acc[2][n], acc[3][n]);
            *(float4*)&P2[n * PNODE + o * PST + cb] = st;
        }
    }
    if (t < 32) {
        float wb[32];
        #pragma unroll
        for (int i = 0; i < 32; i++) wb[i] = w2r[i * SLOTS + 1024 + t];
        #pragma unroll
        for (int n = 0; n < NB; n++) {
            float b = 0.f;
            #pragma unroll
            for (int j = 0; j < 8; j++) {
                float4 xq = *(const float4*)&xs[n][4 * j];
                b += xq.x * wb[4 * j] + xq.y * wb[4 * j + 1]
                   + xq.z * wb[4 * j + 2] + xq.w * wb[4 * j + 3];
            }
            *(float4*)&P2[n * PNODE + t * PST + 32] = make_float4(b, 0.f, 0.f, 0.f);
        }
    }
    __syncthreads();

    // ---- Phase B: 32-lane group per edge; h prefetched one edge ahead ----
    int ebase = rowptr_s[n0];
    int eend  = rowptr_s[n0 + NB];
    int grp = t >> 5;
    int pos = ebase + grp;
    int e_c = 0, src_c = 0;
    float4 hq[8];
    if (pos < eend) {
        e_c = csr_s[pos];
        src_c = ei[e_c];
        const float* hb = &hbuf[(size_t)e_c * 32];
        #pragma unroll
        for (int b = 0; b < 8; b++) hq[b] = *(const float4*)&hb[4 * b];
    }
    while (pos < eend) {
        int pos_n = pos + 8;
        int e_n = 0, src_n = 0;
        float4 hq_n[8];
        if (pos_n < eend) {
            e_n = csr_s[pos_n];
            src_n = ei[e_n];
            const float* hbn = &hbuf[(size_t)e_n * 32];
            #pragma unroll
            for (int b = 0; b < 8; b++) hq_n[b] = *(const float4*)&hbn[4 * b];
        }
        const float* Pn = &P2[(src_c - n0) * PNODE + o * PST];
        float msg = Pn[32];                              // bias slot
        #pragma unroll
        for (int b = 0; b < 8; b++) {
            float4 pq = *(const float4*)&Pn[4 * b];      // ds_read_b128
            msg += hq[b].x * pq.x + hq[b].y * pq.y
                 + hq[b].z * pq.z + hq[b].w * pq.w;
        }
        msgbuf[(size_t)e_c * 32 + o] = msg;              // coalesced 128B per group
        pos = pos_n; e_c = e_n; src_c = src_n;
        #pragma unroll
        for (int b = 0; b < 8; b++) hq[b] = hq_n[b];
    }
}

// ---------------- combine: deterministic dst-gather + x@root + bias -> BN -> ReLU -------
__global__ __launch_bounds__(256) void k_combine(const float* __restrict__ x_in,
        const float* __restrict__ msgbuf,
        const int* __restrict__ rowptr_d, const int* __restrict__ csr_d,
        const float* __restrict__ root, const float* __restrict__ bias,
        const float* __restrict__ bng, const float* __restrict__ bnb,
        const float* __restrict__ bnm, const float* __restrict__ bnv,
        float* __restrict__ x_out) {
    __shared__ float xs[8][32];
    int t = threadIdx.x;
    int n0 = blockIdx.x * 8;
    xs[t >> 5][t & 31] = x_in[n0 * 32 + t];
    __syncthreads();
    int k = t >> 5, o = t & 31, n = n0 + k;
    float r = bias[o];
    #pragma unroll
    for (int i = 0; i < 32; i++) r += xs[k][i] * root[i * 32 + o];
    int lo = rowptr_d[n], hi = rowptr_d[n + 1];
    float a = 0.f;
    int e_c = (lo < hi) ? csr_d[lo] : 0;
    for (int idx = lo; idx < hi; idx++) {
        int e_n = (idx + 1 < hi) ? csr_d[idx + 1] : 0;   // prefetch next eid
        a += msgbuf[(size_t)e_c * 32 + o];               // fixed (sorted) order
        e_c = e_n;
    }
    a /= fmaxf((float)(hi - lo), 1.f);
    float val = a + r;
    val = (val - bnm[o]) * rsqrtf(bnv[o] + EPSV) * bng[o] + bnb[o];
    val = fmaxf(val, 0.f);
    x_out[(size_t)n * 32 + o] = val;
}

// ---------------- pool + readout: one block per graph, fixed reduction tree -------------
__global__ __launch_bounds__(256) void k_pool(const float* __restrict__ xout2,
        const int* __restrict__ batch,
        const float* __restrict__ r1w, const float* __restrict__ r1b,
        const float* __restrict__ r2w, const float* __restrict__ r2b,
        float* __restrict__ out) {
    __shared__ float red[8][32];
    __shared__ float pooled[32];
    __shared__ float zred[16];
    int g = blockIdx.x;
    int t = threadIdx.x, k = t >> 5, o = t & 31;
    int lo = 0, hi = NN;
    while (lo < hi) { int m = (lo + hi) >> 1; if (batch[m] < g) lo = m + 1; else hi = m; }
    int lb = lo;
    lo = 0; hi = NN;
    while (lo < hi) { int m = (lo + hi) >> 1; if (batch[m] < g + 1) lo = m + 1; else hi = m; }
    int ub = lo;
    float s = 0.f;
    for (int n = lb + k; n < ub; n += 8) s += xout2[(size_t)n * 32 + o];
    red[k][o] = s;
    __syncthreads();
    if (k == 0) {
        float tot = red[0][o];
        #pragma unroll
        for (int kk = 1; kk < 8; kk++) tot += red[kk][o];   // fixed order
        pooled[o] = tot / fmaxf((float)(ub - lb), 1.f);
    }
    __syncthreads();
    if (t < 16) {
        float z = r1b[t];
        #pragma unroll
        for (int c = 0; c < 32; c++) z += pooled[c] * r1w[c * 16 + t];
        zred[t] = fmaxf(z, 0.f) * r2w[t];
    }
    __syncthreads();
    if (t == 0) {
        float acc = r2b[0];
        #pragma unroll
        for (int j = 0; j < 16; j++) acc += zred[j];
        out[g] = acc;
    }
}

extern "C" void kernel_launch(void* const* d_in, const int* in_sizes, int n_in,
                              void* d_out, int out_size, void* d_ws, size_t ws_size,
                              hipStream_t stream) {
    const float* x       = (const float*)d_in[0];
    const float* eattr   = (const float*)d_in[1];
    const float* e1_w1   = (const float*)d_in[2];
    const float* e1_b1   = (const float*)d_in[3];
    const float* e1_w2   = (const float*)d_in[4];
    const float* e1_b2   = (const float*)d_in[5];
    const float* root1   = (const float*)d_in[6];
    const float* bias1   = (const float*)d_in[7];
    const float* e2_w1   = (const float*)d_in[8];
    const float* e2_b1   = (const float*)d_in[9];
    const float* e2_w2   = (const float*)d_in[10];
    const float* e2_b2   = (const float*)d_in[11];
    const float* root2   = (const float*)d_in[12];
    const float* bias2   = (const float*)d_in[13];
    const float* bn1_g   = (const float*)d_in[14];
    const float* bn1_b   = (const float*)d_in[15];
    const float* bn1_m   = (const float*)d_in[16];
    const float* bn1_v   = (const float*)d_in[17];
    const float* bn2_g   = (const float*)d_in[18];
    const float* bn2_b   = (const float*)d_in[19];
    const float* bn2_m   = (const float*)d_in[20];
    const float* bn2_v   = (const float*)d_in[21];
    const float* r1_w    = (const float*)d_in[22];
    const float* r1_b    = (const float*)d_in[23];
    const float* r2_w    = (const float*)d_in[24];
    const float* r2_b    = (const float*)d_in[25];
    const int*   ei      = (const int*)d_in[26];
    const int*   batch   = (const int*)d_in[27];

    // workspace layout (bytes)
    char* ws = (char*)d_ws;
    float* hbuf1    = (float*)(ws);                 // 12,800,000
    float* hbuf2    = (float*)(ws + 12800000);      // 12,800,000
    float* msgbuf   = (float*)(ws + 25600000);      // 12,800,000
    float* w2r1     = (float*)(ws + 38400000);      // 135,168
    float* w2r2     = (float*)(ws + 38535168);      // 135,168
    float* xmid     = (float*)(ws + 38670336);      // 1,280,000
    float* xout2    = (float*)(ws + 39950336);      // 1,280,000
    // ---- zero region start (80,000 B) ----
    int*   cnt      = (int*)  (ws + 41230336);      // 40,000 (dst in-degree)
    int*   deg      = (int*)  (ws + 41270336);      // 40,000 (src out-degree)
    // ---- zero region end ----
    int*   rowptr_s = (int*)  (ws + 41310336);      // 40,064
    int*   rowptr_d = (int*)  (ws + 41350400);      // 40,064
    int*   cursor_s = (int*)  (ws + 41390464);      // 40,000
    int*   cursor_d = (int*)  (ws + 41430464);      // 40,000
    int*   csr_s    = (int*)  (ws + 41470464);      // 400,000
    int*   csr_d    = (int*)  (ws + 41870464);      // 400,000
    // total ~42.3 MB

    hipMemsetAsync(ws + 41230336, 0, 80000, stream);   // cnt+deg

    k_init<<<EBLK + WBLK, 256, 0, stream>>>(eattr, e1_w1, e1_b1, e2_w1, e2_b1, ei,
                                            hbuf1, hbuf2, cnt, deg,
                                            e1_w2, e1_b2, e2_w2, e2_b2, w2r1, w2r2);
    k_scan2<<<1, 1024, 0, stream>>>(deg, cnt, rowptr_s, cursor_s, rowptr_d, cursor_d);
    k_scatter2<<<(EE + 255) / 256, 256, 0, stream>>>(ei, cursor_s, csr_s, cursor_d, csr_d);
    k_sortrows<<<(NN + 255) / 256, 256, 0, stream>>>(rowptr_d, csr_d);

    // ---- layer 1 ----
    k_fused3<<<NN / NB, 256, 0, stream>>>(x, hbuf1, w2r1, ei, rowptr_s, csr_s, msgbuf);
    k_combine<<<NN / 8, 256, 0, stream>>>(x, msgbuf, rowptr_d, csr_d, root1, bias1,
                                          bn1_g, bn1_b, bn1_m, bn1_v, xmid);

    // ---- layer 2 ----
    k_fused3<<<NN / NB, 256, 0, stream>>>(xmid, hbuf2, w2r2, ei, rowptr_s, csr_s, msgbuf);
    k_combine<<<NN / 8, 256, 0, stream>>>(xmid, msgbuf, rowptr_d, csr_d, root2, bias2,
                                          bn2_g, bn2_b, bn2_m, bn2_v, xout2);

    // ---- pool + readout (deterministic, one block per graph) ----
    k_pool<<<GG, 256, 0, stream>>>(xout2, batch, r1_w, r1_b, r2_w, r2_b, (float*)d_out);
}

// Round 11
// 319.077 us; speedup vs baseline: 1.3088x; 1.0197x over previous
//
#include <hip/hip_runtime.h>

#define NN 10000
#define EE 100000
#define CC 32
#define GG 64
#define EPSV 1e-5f
#define NB 4               // src nodes per fused block
#define SLOTS 1056         // 32*32 P-slots + 32 bias slots (w2r layout [i][slot])
#define PST 36             // P2 c-stride per o-row (c=0..31 data, 32 bias, 33..35 pad)
#define PNODE (32*PST)     // 1152 floats per node in LDS
#define EBLK (EE/8)        // 12500 edge blocks in k_init
#define WBLK 160           // w2t blocks in k_init: 5 per i, i=0..31

// ---------------- k_init: per-edge h (both layers, 32 f/edge) + hists + w transpose ----
__global__ __launch_bounds__(256) void k_init(const float* __restrict__ edge_attr,
        const float* __restrict__ w1a, const float* __restrict__ b1a,
        const float* __restrict__ w1b, const float* __restrict__ b1b,
        const int* __restrict__ ei,
        float* __restrict__ hbuf1, float* __restrict__ hbuf2,
        int* __restrict__ cnt, int* __restrict__ deg,
        const float* __restrict__ w2a, const float* __restrict__ b2a,
        const float* __restrict__ w2b, const float* __restrict__ b2b,
        float* __restrict__ w2r1, float* __restrict__ w2r2) {
    int blk = blockIdx.x;
    int t = threadIdx.x;
    if (blk < EBLK) {
        int e = blk * 8 + (t >> 5);
        int o = t & 31;
        float4 a = *(const float4*)&edge_attr[(size_t)e * 4];
        float ha = fmaxf(a.x * w1a[o] + a.y * w1a[32 + o] + a.z * w1a[64 + o] + a.w * w1a[96 + o] + b1a[o], 0.f);
        float hb = fmaxf(a.x * w1b[o] + a.y * w1b[32 + o] + a.z * w1b[64 + o] + a.w * w1b[96 + o] + b1b[o], 0.f);
        hbuf1[(size_t)e * 32 + o] = ha;
        hbuf2[(size_t)e * 32 + o] = hb;
        if (o == 0) {
            atomicAdd(&cnt[ei[EE + e]], 1);   // dst in-degree (int: deterministic)
            atomicAdd(&deg[ei[e]], 1);        // src out-degree
        }
    } else {
        int b2i = blk - EBLK;                 // 0..159
        int s = (b2i % 5) * 256 + t;
        int i = b2i / 5;
        if (s < SLOTS) {
            float va = (s < 1024) ? w2a[(s >> 5) * 1024 + i * 32 + (s & 31)]
                                  : b2a[i * 32 + (s - 1024)];
            float vb = (s < 1024) ? w2b[(s >> 5) * 1024 + i * 32 + (s & 31)]
                                  : b2b[i * 32 + (s - 1024)];
            w2r1[i * SLOTS + s] = va;
            w2r2[i * SLOTS + s] = vb;
        }
    }
}

// ---------------- single packed scan: (deg,cnt) -> (rowptr_s,cursor_s,rowptr_d,cursor_d)
// R11: u64-packed (hi=deg, lo=cnt) -> one scan pass instead of two (halves barriers).
__global__ __launch_bounds__(1024) void k_scan2(const int* __restrict__ deg,
        const int* __restrict__ cnt,
        int* __restrict__ rowptr_s, int* __restrict__ cursor_s,
        int* __restrict__ rowptr_d, int* __restrict__ cursor_d) {
    __shared__ unsigned long long buf[1024];
    int t = threadIdx.x;
    int base = t * 10;
    unsigned long long v[10]; unsigned long long s = 0;
    #pragma unroll
    for (int k = 0; k < 10; k++) {
        int idx = base + k;
        v[k] = (idx < NN) ? (((unsigned long long)deg[idx] << 32) | (unsigned)cnt[idx]) : 0ull;
        s += v[k];
    }
    buf[t] = s;
    for (int off = 1; off < 1024; off <<= 1) {
        __syncthreads();
        unsigned long long val = buf[t] + ((t >= off) ? buf[t - off] : 0ull);
        __syncthreads();
        buf[t] = val;
    }
    __syncthreads();
    unsigned long long carry = (t > 0) ? buf[t - 1] : 0ull;
    #pragma unroll
    for (int k = 0; k < 10; k++) {
        int idx = base + k;
        if (idx < NN) {
            int hs = (int)(carry >> 32), lc = (int)(carry & 0xffffffffull);
            rowptr_s[idx] = hs; cursor_s[idx] = hs;
            rowptr_d[idx] = lc; cursor_d[idx] = lc;
        }
        carry += v[k];
    }
    if (t == 1023) {
        rowptr_s[NN] = (int)(buf[1023] >> 32);
        rowptr_d[NN] = (int)(buf[1023] & 0xffffffffull);
    }
}

// ---------------- scatter: build dst-CSR + permute h/src into src-CSR position order ----
// R11: hperm[ps]=h[e], srcp[ps]=src, posmap[e]=ps  ->  fused3 Phase B becomes pure
// streaming (no csr/ei indirection). Layout is race-dependent but within-run
// consistent; summation order in k_combine stays fixed by sorted csr_d.
__global__ __launch_bounds__(256) void k_scatter(const int* __restrict__ ei,
        const float* __restrict__ hbuf1, const float* __restrict__ hbuf2,
        int* __restrict__ cursor_s, int* __restrict__ cursor_d,
        int* __restrict__ csr_d, int* __restrict__ posmap, int* __restrict__ srcp,
        float* __restrict__ hperm1, float* __restrict__ hperm2) {
    int e = blockIdx.x * 256 + threadIdx.x;
    if (e >= EE) return;
    int src = ei[e], dst = ei[EE + e];
    int ps = atomicAdd(&cursor_s[src], 1);
    int pd = atomicAdd(&cursor_d[dst], 1);
    csr_d[pd] = e;
    posmap[e] = ps;
    srcp[ps] = src;
    const float4* s1 = (const float4*)&hbuf1[(size_t)e * 32];
    const float4* s2 = (const float4*)&hbuf2[(size_t)e * 32];
    float4* d1 = (float4*)&hperm1[(size_t)ps * 32];
    float4* d2 = (float4*)&hperm2[(size_t)ps * 32];
    #pragma unroll
    for (int i = 0; i < 8; i++) d1[i] = s1[i];
    #pragma unroll
    for (int i = 0; i < 8; i++) d2[i] = s2[i];
}

// ---------------- sort each dst row by edge id (determinism of gather order) ----------------
__global__ void k_sortrows(const int* __restrict__ rowptr_d, int* __restrict__ csr_d) {
    int n = blockIdx.x * blockDim.x + threadIdx.x;
    if (n >= NN) return;
    int lo = rowptr_d[n], hi = rowptr_d[n + 1];
    for (int i = lo + 1; i < hi; i++) {
        int v = csr_d[i];
        int j = i - 1;
        while (j >= lo && csr_d[j] > v) { csr_d[j + 1] = csr_d[j]; j--; }
        csr_d[j + 1] = v;
    }
}

// ---------------- fused NNConv: P in LDS + streaming edge pass -> msgbuf[pos] ----------
__global__ __launch_bounds__(256, 3) void k_fused3(const float* __restrict__ x,
        const float* __restrict__ hperm,
        const float* __restrict__ w2r,
        const int* __restrict__ rowptr_s, const int* __restrict__ srcp,
        float* __restrict__ msgbuf) {
    __shared__ float xs[NB][32];
    __shared__ float P2[NB * PNODE];     // 4*1152*4 = 18,432 B
    int t = threadIdx.x;
    int o = t & 31;
    int cb = 4 * (t >> 5);               // base c (0,4,...,28)
    int n0 = blockIdx.x * NB;

    if (t < NB * 32) xs[t >> 5][t & 31] = x[n0 * 32 + t];
    __syncthreads();

    // ---- Phase A: P2[n][o][c] = sum_i x[n,i] * w2r[i][c*32+o]; bias at slot 32 ----
    {
        float acc[4][NB];
        #pragma unroll
        for (int k = 0; k < 4; k++)
            #pragma unroll
            for (int n = 0; n < NB; n++) acc[k][n] = 0.f;
        #pragma unroll
        for (int j = 0; j < 8; j++) {
            float wk[4][4];
            #pragma unroll
            for (int r = 0; r < 4; r++)
                #pragma unroll
                for (int k = 0; k < 4; k++)
                    wk[r][k] = w2r[(4 * j + r) * SLOTS + (cb + k) * 32 + o];
            #pragma unroll
            for (int n = 0; n < NB; n++) {
                float4 xq = *(const float4*)&xs[n][4 * j];
                #pragma unroll
                for (int k = 0; k < 4; k++)
                    acc[k][n] += xq.x * wk[0][k] + xq.y * wk[1][k]
                               + xq.z * wk[2][k] + xq.w * wk[3][k];
            }
        }
        #pragma unroll
        for (int n = 0; n < NB; n++) {
            float4 st = make_float4(acc[0][n], acc[1][n], acc[2][n], acc[3][n]);
            *(float4*)&P2[n * PNODE + o * PST + cb] = st;
        }
    }
    if (t < 32) {
        float wb[32];
        #pragma unroll
        for (int i = 0; i < 32; i++) wb[i] = w2r[i * SLOTS + 1024 + t];
        #pragma unroll
        for (int n = 0; n < NB; n++) {
            float b = 0.f;
            #pragma unroll
            for (int j = 0; j < 8; j++) {
                float4 xq = *(const float4*)&xs[n][4 * j];
                b += xq.x * wb[4 * j] + xq.y * wb[4 * j + 1]
                   + xq.z * wb[4 * j + 2] + xq.w * wb[4 * j + 3];
            }
            *(float4*)&P2[n * PNODE + t * PST + 32] = make_float4(b, 0.f, 0.f, 0.f);
        }
    }
    __syncthreads();

    // ---- Phase B: streaming over src-CSR positions; no indirection ----
    int ebase = rowptr_s[n0];
    int eend  = rowptr_s[n0 + NB];
    int grp = t >> 5;
    int pos = ebase + grp;
    int src_c = 0;
    float4 hq[8];
    if (pos < eend) {
        src_c = srcp[pos];
        const float* hb = &hperm[(size_t)pos * 32];
        #pragma unroll
        for (int b = 0; b < 8; b++) hq[b] = *(const float4*)&hb[4 * b];
    }
    while (pos < eend) {
        int pos_n = pos + 8;
        int src_n = 0;
        float4 hq_n[8];
        if (pos_n < eend) {                 // prefetch next position (streaming)
            src_n = srcp[pos_n];
            const float* hbn = &hperm[(size_t)pos_n * 32];
            #pragma unroll
            for (int b = 0; b < 8; b++) hq_n[b] = *(const float4*)&hbn[4 * b];
        }
        const float* Pn = &P2[(src_c - n0) * PNODE + o * PST];
        float msg = Pn[32];                              // bias slot
        #pragma unroll
        for (int b = 0; b < 8; b++) {
            float4 pq = *(const float4*)&Pn[4 * b];      // ds_read_b128
            msg += hq[b].x * pq.x + hq[b].y * pq.y
                 + hq[b].z * pq.z + hq[b].w * pq.w;
        }
        msgbuf[(size_t)pos * 32 + o] = msg;              // streaming 128B store
        pos = pos_n; src_c = src_n;
        #pragma unroll
        for (int b = 0; b < 8; b++) hq[b] = hq_n[b];
    }
}

// ---------------- combine: deterministic dst-gather + x@root + bias -> BN -> ReLU -------
__global__ __launch_bounds__(256) void k_combine(const float* __restrict__ x_in,
        const float* __restrict__ msgbuf,
        const int* __restrict__ rowptr_d, const int* __restrict__ csr_d,
        const int* __restrict__ posmap,
        const float* __restrict__ root, const float* __restrict__ bias,
        const float* __restrict__ bng, const float* __restrict__ bnb,
        const float* __restrict__ bnm, const float* __restrict__ bnv,
        float* __restrict__ x_out) {
    __shared__ float xs[8][32];
    int t = threadIdx.x;
    int n0 = blockIdx.x * 8;
    xs[t >> 5][t & 31] = x_in[n0 * 32 + t];
    __syncthreads();
    int k = t >> 5, o = t & 31, n = n0 + k;
    float r = bias[o];
    #pragma unroll
    for (int i = 0; i < 32; i++) r += xs[k][i] * root[i * 32 + o];
    int lo = rowptr_d[n], hi = rowptr_d[n + 1];
    float a = 0.f;
    int p_c = 0;
    if (lo < hi) p_c = posmap[csr_d[lo]];
    for (int idx = lo; idx < hi; idx++) {
        int p_n = (idx + 1 < hi) ? posmap[csr_d[idx + 1]] : 0;   // prefetch next pos
        a += msgbuf[(size_t)p_c * 32 + o];               // fixed (sorted-by-e) order
        p_c = p_n;
    }
    a /= fmaxf((float)(hi - lo), 1.f);
    float val = a + r;
    val = (val - bnm[o]) * rsqrtf(bnv[o] + EPSV) * bng[o] + bnb[o];
    val = fmaxf(val, 0.f);
    x_out[(size_t)n * 32 + o] = val;
}

// ---------------- pool + readout: one block per graph, fixed reduction tree -------------
__global__ __launch_bounds__(256) void k_pool(const float* __restrict__ xout2,
        const int* __restrict__ batch,
        const float* __restrict__ r1w, const float* __restrict__ r1b,
        const float* __restrict__ r2w, const float* __restrict__ r2b,
        float* __restrict__ out) {
    __shared__ float red[8][32];
    __shared__ float pooled[32];
    __shared__ float zred[16];
    int g = blockIdx.x;
    int t = threadIdx.x, k = t >> 5, o = t & 31;
    int lo = 0, hi = NN;
    while (lo < hi) { int m = (lo + hi) >> 1; if (batch[m] < g) lo = m + 1; else hi = m; }
    int lb = lo;
    lo = 0; hi = NN;
    while (lo < hi) { int m = (lo + hi) >> 1; if (batch[m] < g + 1) lo = m + 1; else hi = m; }
    int ub = lo;
    float s = 0.f;
    for (int n = lb + k; n < ub; n += 8) s += xout2[(size_t)n * 32 + o];
    red[k][o] = s;
    __syncthreads();
    if (k == 0) {
        float tot = red[0][o];
        #pragma unroll
        for (int kk = 1; kk < 8; kk++) tot += red[kk][o];   // fixed order
        pooled[o] = tot / fmaxf((float)(ub - lb), 1.f);
    }
    __syncthreads();
    if (t < 16) {
        float z = r1b[t];
        #pragma unroll
        for (int c = 0; c < 32; c++) z += pooled[c] * r1w[c * 16 + t];
        zred[t] = fmaxf(z, 0.f) * r2w[t];
    }
    __syncthreads();
    if (t == 0) {
        float acc = r2b[0];
        #pragma unroll
        for (int j = 0; j < 16; j++) acc += zred[j];
        out[g] = acc;
    }
}

extern "C" void kernel_launch(void* const* d_in, const int* in_sizes, int n_in,
                              void* d_out, int out_size, void* d_ws, size_t ws_size,
                              hipStream_t stream) {
    const float* x       = (const float*)d_in[0];
    const float* eattr   = (const float*)d_in[1];
    const float* e1_w1   = (const float*)d_in[2];
    const float* e1_b1   = (const float*)d_in[3];
    const float* e1_w2   = (const float*)d_in[4];
    const float* e1_b2   = (const float*)d_in[5];
    const float* root1   = (const float*)d_in[6];
    const float* bias1   = (const float*)d_in[7];
    const float* e2_w1   = (const float*)d_in[8];
    const float* e2_b1   = (const float*)d_in[9];
    const float* e2_w2   = (const float*)d_in[10];
    const float* e2_b2   = (const float*)d_in[11];
    const float* root2   = (const float*)d_in[12];
    const float* bias2   = (const float*)d_in[13];
    const float* bn1_g   = (const float*)d_in[14];
    const float* bn1_b   = (const float*)d_in[15];
    const float* bn1_m   = (const float*)d_in[16];
    const float* bn1_v   = (const float*)d_in[17];
    const float* bn2_g   = (const float*)d_in[18];
    const float* bn2_b   = (const float*)d_in[19];
    const float* bn2_m   = (const float*)d_in[20];
    const float* bn2_v   = (const float*)d_in[21];
    const float* r1_w    = (const float*)d_in[22];
    const float* r1_b    = (const float*)d_in[23];
    const float* r2_w    = (const float*)d_in[24];
    const float* r2_b    = (const float*)d_in[25];
    const int*   ei      = (const int*)d_in[26];
    const int*   batch   = (const int*)d_in[27];

    // workspace layout (bytes)
    char* ws = (char*)d_ws;
    float* hbuf1    = (float*)(ws);                 // 12,800,000
    float* hbuf2    = (float*)(ws + 12800000);      // 12,800,000
    float* hperm1   = (float*)(ws + 25600000);      // 12,800,000
    float* hperm2   = (float*)(ws + 38400000);      // 12,800,000
    float* msgbuf   = (float*)(ws + 51200000);      // 12,800,000
    float* w2r1     = (float*)(ws + 64000000);      // 135,168
    float* w2r2     = (float*)(ws + 64135168);      // 135,168
    float* xmid     = (float*)(ws + 64270336);      // 1,280,000
    float* xout2    = (float*)(ws + 65550336);      // 1,280,000
    // ---- zero region start (80,000 B) ----
    int*   cnt      = (int*)  (ws + 66830336);      // 40,000 (dst in-degree)
    int*   deg      = (int*)  (ws + 66870336);      // 40,000 (src out-degree)
    // ---- zero region end ----
    int*   rowptr_s = (int*)  (ws + 66910336);      // 40,064
    int*   rowptr_d = (int*)  (ws + 66950400);      // 40,064
    int*   cursor_s = (int*)  (ws + 66990464);      // 40,000
    int*   cursor_d = (int*)  (ws + 67030464);      // 40,000
    int*   csr_d    = (int*)  (ws + 67070464);      // 400,000
    int*   posmap   = (int*)  (ws + 67470464);      // 400,000
    int*   srcp     = (int*)  (ws + 67870464);      // 400,000
    // total ~68.3 MB

    hipMemsetAsync(ws + 66830336, 0, 80000, stream);   // cnt+deg

    k_init<<<EBLK + WBLK, 256, 0, stream>>>(eattr, e1_w1, e1_b1, e2_w1, e2_b1, ei,
                                            hbuf1, hbuf2, cnt, deg,
                                            e1_w2, e1_b2, e2_w2, e2_b2, w2r1, w2r2);
    k_scan2<<<1, 1024, 0, stream>>>(deg, cnt, rowptr_s, cursor_s, rowptr_d, cursor_d);
    k_scatter<<<(EE + 255) / 256, 256, 0, stream>>>(ei, hbuf1, hbuf2,
                                                    cursor_s, cursor_d,
                                                    csr_d, posmap, srcp, hperm1, hperm2);
    k_sortrows<<<(NN + 255) / 256, 256, 0, stream>>>(rowptr_d, csr_d);

    // ---- layer 1 ----
    k_fused3<<<NN / NB, 256, 0, stream>>>(x, hperm1, w2r1, rowptr_s, srcp, msgbuf);
    k_combine<<<NN / 8, 256, 0, stream>>>(x, msgbuf, rowptr_d, csr_d, posmap, root1, bias1,
                                          bn1_g, bn1_b, bn1_m, bn1_v, xmid);

    // ---- layer 2 ----
    k_fused3<<<NN / NB, 256, 0, stream>>>(xmid, hperm2, w2r2, rowptr_s, srcp, msgbuf);
    k_combine<<<NN / 8, 256, 0, stream>>>(xmid, msgbuf, rowptr_d, csr_d, posmap, root2, bias2,
                                          bn2_g, bn2_b, bn2_m, bn2_v, xout2);

    // ---- pool + readout (deterministic, one block per graph) ----
    k_pool<<<GG, 256, 0, stream>>>(xout2, batch, r1_w, r1_b, r2_w, r2_b, (float*)d_out);
}

// Round 12
// 306.587 us; speedup vs baseline: 1.3621x; 1.0407x over previous
//
#include <hip/hip_runtime.h>

#define NN 10000
#define EE 100000
#define CC 32
#define GG 64
#define EPSV 1e-5f
#define NB 4               // src nodes per fused block
#define SLOTS 1056         // 32*32 P-slots + 32 bias slots (w2r layout [i][slot])
#define PST 36             // P2 c-stride per o-row (c=0..31 data, 32 bias, 33..35 pad)
#define PNODE (32*PST)     // 1152 floats per node in LDS
#define IBLK 391           // hist blocks (1 thread/edge)
#define WBLK 160           // w2t blocks: 5 per i, i=0..31
#define HBLK (EE/8)        // 12500 hedge blocks in k_hsd
#define SBLK 40            // sort/dmap blocks in k_hsd (40*256 >= NN)

// ---------------- k_init: degree hists + weight transpose ----------------
__global__ __launch_bounds__(256) void k_init(const int* __restrict__ ei,
        int* __restrict__ cnt, int* __restrict__ deg,
        const float* __restrict__ w2a, const float* __restrict__ b2a,
        const float* __restrict__ w2b, const float* __restrict__ b2b,
        float* __restrict__ w2r1, float* __restrict__ w2r2) {
    int blk = blockIdx.x;
    int t = threadIdx.x;
    if (blk < IBLK) {
        int e = blk * 256 + t;
        if (e < EE) {
            atomicAdd(&deg[ei[e]], 1);        // src out-degree
            atomicAdd(&cnt[ei[EE + e]], 1);   // dst in-degree
        }
    } else {
        int b2i = blk - IBLK;                 // 0..159
        int s = (b2i % 5) * 256 + t;
        int i = b2i / 5;
        if (s < SLOTS) {
            float va = (s < 1024) ? w2a[(s >> 5) * 1024 + i * 32 + (s & 31)]
                                  : b2a[i * 32 + (s - 1024)];
            float vb = (s < 1024) ? w2b[(s >> 5) * 1024 + i * 32 + (s & 31)]
                                  : b2b[i * 32 + (s - 1024)];
            w2r1[i * SLOTS + s] = va;
            w2r2[i * SLOTS + s] = vb;
        }
    }
}

// ---------------- single packed scan: (deg,cnt) -> rowptrs + cursors ----------------
__global__ __launch_bounds__(1024) void k_scan2(const int* __restrict__ deg,
        const int* __restrict__ cnt,
        int* __restrict__ rowptr_s, int* __restrict__ cursor_s,
        int* __restrict__ rowptr_d, int* __restrict__ cursor_d) {
    __shared__ unsigned long long buf[1024];
    int t = threadIdx.x;
    int base = t * 10;
    unsigned long long v[10]; unsigned long long s = 0;
    #pragma unroll
    for (int k = 0; k < 10; k++) {
        int idx = base + k;
        v[k] = (idx < NN) ? (((unsigned long long)deg[idx] << 32) | (unsigned)cnt[idx]) : 0ull;
        s += v[k];
    }
    buf[t] = s;
    for (int off = 1; off < 1024; off <<= 1) {
        __syncthreads();
        unsigned long long val = buf[t] + ((t >= off) ? buf[t - off] : 0ull);
        __syncthreads();
        buf[t] = val;
    }
    __syncthreads();
    unsigned long long carry = (t > 0) ? buf[t - 1] : 0ull;
    #pragma unroll
    for (int k = 0; k < 10; k++) {
        int idx = base + k;
        if (idx < NN) {
            int hs = (int)(carry >> 32), lc = (int)(carry & 0xffffffffull);
            rowptr_s[idx] = hs; cursor_s[idx] = hs;
            rowptr_d[idx] = lc; cursor_d[idx] = lc;
        }
        carry += v[k];
    }
    if (t == 1023) {
        rowptr_s[NN] = (int)(buf[1023] >> 32);
        rowptr_d[NN] = (int)(buf[1023] & 0xffffffffull);
    }
}

// ---------------- scatter: src-position map + dst-CSR ----------------
__global__ __launch_bounds__(256) void k_scatter(const int* __restrict__ ei,
        int* __restrict__ cursor_s, int* __restrict__ cursor_d,
        int* __restrict__ csr_d, int* __restrict__ posmap, int* __restrict__ eidp) {
    int e = blockIdx.x * 256 + threadIdx.x;
    if (e >= EE) return;
    int src = ei[e], dst = ei[EE + e];
    int ps = atomicAdd(&cursor_s[src], 1);
    int pd = atomicAdd(&cursor_d[dst], 1);
    csr_d[pd] = e;
    posmap[e] = ps;
    eidp[ps] = e;
}

// ---------------- k_hsd: h into src-pos order (both layers) + row-sort + dmap ----------
// dmap[ps] = final dst-sorted slot of the edge at src-position ps. Deterministic:
// sort is by edge id; posmap/ps are raced but within-run consistent.
__global__ __launch_bounds__(256) void k_hsd(const int* __restrict__ eidp,
        const float* __restrict__ edge_attr,
        const float* __restrict__ w1a, const float* __restrict__ b1a,
        const float* __restrict__ w1b, const float* __restrict__ b1b,
        float* __restrict__ hperm1, float* __restrict__ hperm2,
        const int* __restrict__ rowptr_d, int* __restrict__ csr_d,
        const int* __restrict__ posmap, int* __restrict__ dmap) {
    int blk = blockIdx.x;
    int t = threadIdx.x;
    if (blk < HBLK) {
        int ps = blk * 8 + (t >> 5);
        int o = t & 31;
        int e = eidp[ps];
        float4 a = *(const float4*)&edge_attr[(size_t)e * 4];
        float h1 = fmaxf(a.x * w1a[o] + a.y * w1a[32 + o] + a.z * w1a[64 + o] + a.w * w1a[96 + o] + b1a[o], 0.f);
        float h2 = fmaxf(a.x * w1b[o] + a.y * w1b[32 + o] + a.z * w1b[64 + o] + a.w * w1b[96 + o] + b1b[o], 0.f);
        hperm1[(size_t)ps * 32 + o] = h1;
        hperm2[(size_t)ps * 32 + o] = h2;
    } else {
        int n = (blk - HBLK) * 256 + t;
        if (n < NN) {
            int lo = rowptr_d[n], hi = rowptr_d[n + 1];
            for (int i = lo + 1; i < hi; i++) {           // insertion sort by edge id
                int v = csr_d[i];
                int j = i - 1;
                while (j >= lo && csr_d[j] > v) { csr_d[j + 1] = csr_d[j]; j--; }
                csr_d[j + 1] = v;
            }
            for (int i = lo; i < hi; i++) dmap[posmap[csr_d[i]]] = i;
        }
    }
}

// ---------------- fused NNConv (R12): src-major Phase B, P-row in registers ----------
// Phase A: P2[n][o][c] in LDS (as before). Phase B: 2 half-wave groups per node;
// each group loads its node's P-row ONCE (9 b128), then streams edges:
// 8 broadcast h loads + 1 dmap load + 32 FMA + 1 coalesced store. Per-edge LDS: 0.
__global__ __launch_bounds__(256, 3) void k_fused3(const float* __restrict__ x,
        const float* __restrict__ hperm,
        const float* __restrict__ w2r,
        const int* __restrict__ rowptr_s, const int* __restrict__ dmap,
        float* __restrict__ msgbuf) {
    __shared__ float xs[NB][32];
    __shared__ float P2[NB * PNODE];     // 4*1152*4 = 18,432 B
    int t = threadIdx.x;
    int o = t & 31;
    int cb = 4 * (t >> 5);
    int n0 = blockIdx.x * NB;

    if (t < NB * 32) xs[t >> 5][t & 31] = x[n0 * 32 + t];
    __syncthreads();

    // ---- Phase A ----
    {
        float acc[4][NB];
        #pragma unroll
        for (int k = 0; k < 4; k++)
            #pragma unroll
            for (int n = 0; n < NB; n++) acc[k][n] = 0.f;
        #pragma unroll
        for (int j = 0; j < 8; j++) {
            float wk[4][4];
            #pragma unroll
            for (int r = 0; r < 4; r++)
                #pragma unroll
                for (int k = 0; k < 4; k++)
                    wk[r][k] = w2r[(4 * j + r) * SLOTS + (cb + k) * 32 + o];
            #pragma unroll
            for (int n = 0; n < NB; n++) {
                float4 xq = *(const float4*)&xs[n][4 * j];
                #pragma unroll
                for (int k = 0; k < 4; k++)
                    acc[k][n] += xq.x * wk[0][k] + xq.y * wk[1][k]
                               + xq.z * wk[2][k] + xq.w * wk[3][k];
            }
        }
        #pragma unroll
        for (int n = 0; n < NB; n++) {
            float4 st = make_float4(acc[0][n], acc[1][n], acc[2][n], acc[3][n]);
            *(float4*)&P2[n * PNODE + o * PST + cb] = st;
        }
    }
    if (t < 32) {
        float wb[32];
        #pragma unroll
        for (int i = 0; i < 32; i++) wb[i] = w2r[i * SLOTS + 1024 + t];
        #pragma unroll
        for (int n = 0; n < NB; n++) {
            float b = 0.f;
            #pragma unroll
            for (int j = 0; j < 8; j++) {
                float4 xq = *(const float4*)&xs[n][4 * j];
                b += xq.x * wb[4 * j] + xq.y * wb[4 * j + 1]
                   + xq.z * wb[4 * j + 2] + xq.w * wb[4 * j + 3];
            }
            *(float4*)&P2[n * PNODE + t * PST + 32] = make_float4(b, 0.f, 0.f, 0.f);
        }
    }
    __syncthreads();

    // ---- Phase B: group = (node, half); P-row -> registers once ----
    int nl   = (t >> 6);                 // wrong if 8 groups; recompute below
    nl = (t >> 5) >> 1;                  // node local 0..3
    int half = (t >> 5) & 1;
    int lo = rowptr_s[n0 + nl];
    int hi = rowptr_s[n0 + nl + 1];
    float4 pr[9];
    #pragma unroll
    for (int b = 0; b < 9; b++) pr[b] = *(const float4*)&P2[nl * PNODE + o * PST + 4 * b];

    int pos = lo + half;
    int dm_c = 0; float4 hq[8];
    if (pos < hi) {
        dm_c = dmap[pos];
        const float* hb = &hperm[(size_t)pos * 32];
        #pragma unroll
        for (int b = 0; b < 8; b++) hq[b] = *(const float4*)&hb[4 * b];
    }
    while (pos < hi) {
        int pos_n = pos + 2;
        int dm_n = 0; float4 hq_n[8];
        if (pos_n < hi) {
            dm_n = dmap[pos_n];
            const float* hbn = &hperm[(size_t)pos_n * 32];
            #pragma unroll
            for (int b = 0; b < 8; b++) hq_n[b] = *(const float4*)&hbn[4 * b];
        }
        float msg = pr[8].x;                             // bias
        #pragma unroll
        for (int b = 0; b < 8; b++)
            msg += hq[b].x * pr[b].x + hq[b].y * pr[b].y
                 + hq[b].z * pr[b].z + hq[b].w * pr[b].w;
        msgbuf[(size_t)dm_c * 32 + o] = msg;             // dst-sorted slot, 128B/group
        pos = pos_n; dm_c = dm_n;
        #pragma unroll
        for (int b = 0; b < 8; b++) hq[b] = hq_n[b];
    }
}

// ---------------- combine: CONTIGUOUS dst-row gather + x@root + bias -> BN -> ReLU -----
__global__ __launch_bounds__(256) void k_combine(const float* __restrict__ x_in,
        const float* __restrict__ msgbuf,
        const int* __restrict__ rowptr_d,
        const float* __restrict__ root, const float* __restrict__ bias,
        const float* __restrict__ bng, const float* __restrict__ bnb,
        const float* __restrict__ bnm, const float* __restrict__ bnv,
        float* __restrict__ x_out) {
    __shared__ float xs[8][32];
    int t = threadIdx.x;
    int n0 = blockIdx.x * 8;
    xs[t >> 5][t & 31] = x_in[n0 * 32 + t];
    __syncthreads();
    int k = t >> 5, o = t & 31, n = n0 + k;
    float r = bias[o];
    #pragma unroll
    for (int i = 0; i < 32; i++) r += xs[k][i] * root[i * 32 + o];
    int lo = rowptr_d[n], hi = rowptr_d[n + 1];
    float a = 0.f;
    for (int idx = lo; idx < hi; idx++)
        a += msgbuf[(size_t)idx * 32 + o];               // contiguous, independent loads
    a /= fmaxf((float)(hi - lo), 1.f);
    float val = a + r;
    val = (val - bnm[o]) * rsqrtf(bnv[o] + EPSV) * bng[o] + bnb[o];
    val = fmaxf(val, 0.f);
    x_out[(size_t)n * 32 + o] = val;
}

// ---------------- pool + readout: one block per graph, fixed reduction tree -------------
__global__ __launch_bounds__(256) void k_pool(const float* __restrict__ xout2,
        const int* __restrict__ batch,
        const float* __restrict__ r1w, const float* __restrict__ r1b,
        const float* __restrict__ r2w, const float* __restrict__ r2b,
        float* __restrict__ out) {
    __shared__ float red[8][32];
    __shared__ float pooled[32];
    __shared__ float zred[16];
    int g = blockIdx.x;
    int t = threadIdx.x, k = t >> 5, o = t & 31;
    int lo = 0, hi = NN;
    while (lo < hi) { int m = (lo + hi) >> 1; if (batch[m] < g) lo = m + 1; else hi = m; }
    int lb = lo;
    lo = 0; hi = NN;
    while (lo < hi) { int m = (lo + hi) >> 1; if (batch[m] < g + 1) lo = m + 1; else hi = m; }
    int ub = lo;
    float s = 0.f;
    for (int n = lb + k; n < ub; n += 8) s += xout2[(size_t)n * 32 + o];
    red[k][o] = s;
    __syncthreads();
    if (k == 0) {
        float tot = red[0][o];
        #pragma unroll
        for (int kk = 1; kk < 8; kk++) tot += red[kk][o];
        pooled[o] = tot / fmaxf((float)(ub - lb), 1.f);
    }
    __syncthreads();
    if (t < 16) {
        float z = r1b[t];
        #pragma unroll
        for (int c = 0; c < 32; c++) z += pooled[c] * r1w[c * 16 + t];
        zred[t] = fmaxf(z, 0.f) * r2w[t];
    }
    __syncthreads();
    if (t == 0) {
        float acc = r2b[0];
        #pragma unroll
        for (int j = 0; j < 16; j++) acc += zred[j];
        out[g] = acc;
    }
}

extern "C" void kernel_launch(void* const* d_in, const int* in_sizes, int n_in,
                              void* d_out, int out_size, void* d_ws, size_t ws_size,
                              hipStream_t stream) {
    const float* x       = (const float*)d_in[0];
    const float* eattr   = (const float*)d_in[1];
    const float* e1_w1   = (const float*)d_in[2];
    const float* e1_b1   = (const float*)d_in[3];
    const float* e1_w2   = (const float*)d_in[4];
    const float* e1_b2   = (const float*)d_in[5];
    const float* root1   = (const float*)d_in[6];
    const float* bias1   = (const float*)d_in[7];
    const float* e2_w1   = (const float*)d_in[8];
    const float* e2_b1   = (const float*)d_in[9];
    const float* e2_w2   = (const float*)d_in[10];
    const float* e2_b2   = (const float*)d_in[11];
    const float* root2   = (const float*)d_in[12];
    const float* bias2   = (const float*)d_in[13];
    const float* bn1_g   = (const float*)d_in[14];
    const float* bn1_b   = (const float*)d_in[15];
    const float* bn1_m   = (const float*)d_in[16];
    const float* bn1_v   = (const float*)d_in[17];
    const float* bn2_g   = (const float*)d_in[18];
    const float* bn2_b   = (const float*)d_in[19];
    const float* bn2_m   = (const float*)d_in[20];
    const float* bn2_v   = (const float*)d_in[21];
    const float* r1_w    = (const float*)d_in[22];
    const float* r1_b    = (const float*)d_in[23];
    const float* r2_w    = (const float*)d_in[24];
    const float* r2_b    = (const float*)d_in[25];
    const int*   ei      = (const int*)d_in[26];
    const int*   batch   = (const int*)d_in[27];

    // workspace layout (bytes)
    char* ws = (char*)d_ws;
    float* hperm1   = (float*)(ws);                 // 12,800,000
    float* hperm2   = (float*)(ws + 12800000);      // 12,800,000
    float* msgbuf   = (float*)(ws + 25600000);      // 12,800,000
    float* w2r1     = (float*)(ws + 38400000);      // 135,168
    float* w2r2     = (float*)(ws + 38535168);      // 135,168
    float* xmid     = (float*)(ws + 38670336);      // 1,280,000
    float* xout2    = (float*)(ws + 39950336);      // 1,280,000
    // ---- zero region start (80,000 B) ----
    int*   cnt      = (int*)  (ws + 41230336);      // 40,000 (dst in-degree)
    int*   deg      = (int*)  (ws + 41270336);      // 40,000 (src out-degree)
    // ---- zero region end ----
    int*   rowptr_s = (int*)  (ws + 41310336);      // 40,064
    int*   rowptr_d = (int*)  (ws + 41350400);      // 40,064
    int*   cursor_s = (int*)  (ws + 41390464);      // 40,000
    int*   cursor_d = (int*)  (ws + 41430464);      // 40,000
    int*   csr_d    = (int*)  (ws + 41470464);      // 400,000
    int*   posmap   = (int*)  (ws + 41870464);      // 400,000
    int*   eidp     = (int*)  (ws + 42270464);      // 400,000
    int*   dmap     = (int*)  (ws + 42670464);      // 400,000
    // total ~43.1 MB

    hipMemsetAsync(ws + 41230336, 0, 80000, stream);   // cnt+deg

    k_init<<<IBLK + WBLK, 256, 0, stream>>>(ei, cnt, deg,
                                            e1_w2, e1_b2, e2_w2, e2_b2, w2r1, w2r2);
    k_scan2<<<1, 1024, 0, stream>>>(deg, cnt, rowptr_s, cursor_s, rowptr_d, cursor_d);
    k_scatter<<<IBLK, 256, 0, stream>>>(ei, cursor_s, cursor_d, csr_d, posmap, eidp);
    k_hsd<<<HBLK + SBLK, 256, 0, stream>>>(eidp, eattr, e1_w1, e1_b1, e2_w1, e2_b1,
                                           hperm1, hperm2, rowptr_d, csr_d, posmap, dmap);

    // ---- layer 1 ----
    k_fused3<<<NN / NB, 256, 0, stream>>>(x, hperm1, w2r1, rowptr_s, dmap, msgbuf);
    k_combine<<<NN / 8, 256, 0, stream>>>(x, msgbuf, rowptr_d, root1, bias1,
                                          bn1_g, bn1_b, bn1_m, bn1_v, xmid);

    // ---- layer 2 ----
    k_fused3<<<NN / NB, 256, 0, stream>>>(xmid, hperm2, w2r2, rowptr_s, dmap, msgbuf);
    k_combine<<<NN / 8, 256, 0, stream>>>(xmid, msgbuf, rowptr_d, root2, bias2,
                                          bn2_g, bn2_b, bn2_m, bn2_v, xout2);

    // ---- pool + readout (deterministic, one block per graph) ----
    k_pool<<<GG, 256, 0, stream>>>(xout2, batch, r1_w, r1_b, r2_w, r2_b, (float*)d_out);
}